// Round 17
// baseline (190.483 us; speedup 1.0000x reference)
//
#include <hip/hip_runtime.h>
#include <stdint.h>

typedef __bf16 bf16;
typedef __attribute__((ext_vector_type(8))) __bf16 bfx8;
typedef __attribute__((ext_vector_type(4))) float f32x4;

__device__ inline f32x4 mfma16(bfx8 a, bfx8 b, f32x4 c) {
  return __builtin_amdgcn_mfma_f32_16x16x32_bf16(a, b, c, 0, 0, 0);
}

// Async 16B global->LDS. lbase must be wave-uniform; HW adds lane*16.
__device__ inline void gl16(const bf16* g, bf16* lbase, int lane) {
#if __has_builtin(__builtin_amdgcn_global_load_lds)
  (void)lane;
  __builtin_amdgcn_global_load_lds(
      (const __attribute__((address_space(1))) void*)g,
      (__attribute__((address_space(3))) void*)lbase, 16, 0, 0);
#else
  *(bfx8*)(lbase + lane * 8) = *(const bfx8*)g;
#endif
}

// Image convention: 64x64 bf16 tile stored as 4096 elems, 16B chunks
// XOR-swizzled per row: element (i,e) lives at i*64 + (((e>>3)^(i&7))<<3) + (e&7).
__device__ inline int img_off(int i, int e) {
  return i * 64 + ((((e >> 3) ^ (i & 7)) << 3)) + (e & 7);
}

// Device-scope (agent) acquire/release flag ops for cross-XCD pipelining.
__device__ inline int aload(const int* p) {
  return __hip_atomic_load(p, __ATOMIC_ACQUIRE, __HIP_MEMORY_SCOPE_AGENT);
}
__device__ inline void astore(int* p, int v) {
  __hip_atomic_store(p, v, __ATOMIC_RELEASE, __HIP_MEMORY_SCOPE_AGENT);
}

// ---------------- weight fp32 -> bf16 tile-image (+ flag zeroing) ----------------
struct CvtArgs {
  const float* src[4];
  bf16* dst[4];
  int* flags;  // stflag[512] + obcnt[64]
};
__global__ __launch_bounds__(256) void cvt_w(CvtArgs ca) {
  if (blockIdx.x == 0 && blockIdx.y == 0) {
    for (int i = threadIdx.x; i < 576; i += 256) ca.flags[i] = 0;
  }
  const int z = blockIdx.y;
  const int T = blockIdx.x * 256 + threadIdx.x;  // 4096 threads
  const int n = T >> 3, s8 = T & 7, i = n & 63, nt = n >> 6;
  const float* src = ca.src[z];
  bf16* dst = ca.dst[z];
#pragma unroll
  for (int kt = 0; kt < 8; ++kt) {
    const float* s = src + (size_t)n * 512 + kt * 64 + ((s8 ^ (i & 7)) << 3);
    f32x4 x0 = *(const f32x4*)s, x1 = *(const f32x4*)(s + 4);
    bfx8 v;
    v[0] = (bf16)x0[0]; v[1] = (bf16)x0[1]; v[2] = (bf16)x0[2]; v[3] = (bf16)x0[3];
    v[4] = (bf16)x1[0]; v[5] = (bf16)x1[1]; v[6] = (bf16)x1[2]; v[7] = (bf16)x1[3];
    *(bfx8*)&dst[(size_t)(kt * 8 + nt) * 4096 + i * 64 + s8 * 8] = v;
  }
}

// ---------------- projection GEMM (R16 config, unchanged) ----------------
struct GemmArgs {
  const void* A[3];
  const bf16* Bt[3];
  bf16* ob[3];
  float* of;
  int phi_upto;
};

template <bool AF32, bool OUTF>
__global__ __launch_bounds__(512) void gemm_bt(GemmArgs ga) {
  const int z = blockIdx.z;
  const void* Ag = ga.A[z];
  const bf16* Bg = ga.Bt[z];
  const int tm = blockIdx.x * 64, by = blockIdx.y, tn = by * 128;
  const int tid = threadIdx.x, l = tid & 63, w = tid >> 6;
  const int wm = w >> 2, wn = w & 3, lm = l & 15, lk = l >> 4;

  __shared__ __align__(16) bf16 As[64 * 64];
  __shared__ __align__(16) bf16 Bs[128 * 64];

  f32x4 acc[2][2] = {};

  for (int kt = 0; kt < 8; ++kt) {
    const bf16* bsrc = Bg + (size_t)(kt * 8 + by * 2) * 4096;
#pragma unroll
    for (int q = 0; q < 2; ++q) {
      int cb = (q * 8 + w) * 64;
      gl16(bsrc + (size_t)(cb + l) * 8, &Bs[cb * 8], l);
    }
    if (AF32) {
      int row = tid >> 3, t8 = tid & 7;
      const float* s = (const float*)Ag + (size_t)(tm + row) * 512 + kt * 64 + t8 * 8;
      f32x4 x0 = *(const f32x4*)s, x1 = *(const f32x4*)(s + 4);
      bfx8 v;
      v[0] = (bf16)x0[0]; v[1] = (bf16)x0[1]; v[2] = (bf16)x0[2]; v[3] = (bf16)x0[3];
      v[4] = (bf16)x1[0]; v[5] = (bf16)x1[1]; v[6] = (bf16)x1[2]; v[7] = (bf16)x1[3];
      *(bfx8*)&As[row * 64 + ((t8 ^ (row & 7)) << 3)] = v;
    } else {
      const bf16* asrc = (const bf16*)Ag + ((size_t)((tm >> 6) * 8 + kt) << 12);
      int cb = w * 64;
      gl16(asrc + (size_t)(cb + l) * 8, &As[cb * 8], l);
    }
    __syncthreads();
#pragma unroll
    for (int ks = 0; ks < 2; ++ks) {
      bfx8 af[2], bfr[2];
#pragma unroll
      for (int i = 0; i < 2; ++i) {
        int ra = wm * 32 + i * 16 + lm;
        af[i] = *(const bfx8*)&As[ra * 64 + (((ks * 4 + lk) ^ (ra & 7)) << 3)];
        int rb = wn * 32 + i * 16 + lm;
        bfr[i] = *(const bfx8*)&Bs[rb * 64 + (((ks * 4 + lk) ^ (rb & 7)) << 3)];
      }
#pragma unroll
      for (int i = 0; i < 2; ++i)
#pragma unroll
        for (int j = 0; j < 2; ++j)
          acc[i][j] = mfma16(af[i], bfr[j], acc[i][j]);
    }
    __syncthreads();
  }

  const bool phi = z < ga.phi_upto;
#pragma unroll
  for (int i = 0; i < 2; ++i)
#pragma unroll
    for (int j = 0; j < 2; ++j)
#pragma unroll
      for (int r = 0; r < 4; ++r) {
        int m = tm + wm * 32 + i * 16 + lk * 4 + r;
        int n = tn + wn * 32 + j * 16 + lm;
        float v = acc[i][j][r];
        if (phi) v = v > 0.f ? v + 1.f : __expf(v);
        if (OUTF) {
          ga.of[(size_t)m * 512 + n] = v;
        } else {
          ga.ob[z][((size_t)((m >> 6) * 8 + (n >> 6)) << 12) + img_off(m & 63, n & 63)] =
              (bf16)v;
        }
      }
}

// ---------------- fused attention + output GEMM (one dispatch, flag-pipelined) ----
// 768 blocks x 256 thr, 43008 B LDS -> 3 blocks/CU -> all 768 co-resident.
// Role A (bid<512, c-major): kv-state for (bh,c) -> publish -> spin on 0..c-1 ->
//   chunk output -> count obcnt[rt]. Role B (bid>=512): spin obcnt[rt]==8 -> out GEMM.
struct FusedArgs {
  const bf16 *Qimg, *Kimg, *Vimg, *Woimg;
  bf16 *KVb, *Obsw;
  float* ksums;
  float* out;
  int *stflag, *obcnt;
};

__global__ __launch_bounds__(256, 3) void attn_fused(FusedArgs fa) {
  __shared__ __align__(16) char smem[43008];
  const int bid = blockIdx.x;
  const int tid = threadIdx.x, l = tid & 63, w = tid >> 6;
  const int wm = w >> 1, wn = w & 1, lm = l & 15, lk = l >> 4;

  if (bid < 512) {
    // =================== Role A ===================
    const int c = bid >> 5, bh = bid & 31, b = bh >> 3, h = bh & 7;
    bf16* VTs = (bf16*)smem;                 // [e][j] swizzled (persists)
    bf16* KTs = (bf16*)(smem + 8192);        // [d][j] (phase 1 only)
    bf16* Qs = (bf16*)(smem + 8192);         // phase 2 (overwrites KTs)
    bf16* Ks = (bf16*)(smem + 16384);
    bf16* Ss = (bf16*)(smem + 24576);
    bf16* KVL = (bf16*)(smem + 32768);
    float* ksum_p = (float*)(smem + 40960);  // phase 1 (256 f)
    float* ksum = (float*)(smem + 40960);    // phase 2 (64 f)
    float* den_i = (float*)(smem + 41216);
    float* den_all = (float*)(smem + 41472);
    float* den_p = (float*)(smem + 41728);

    const size_t tb = (size_t)((b * 16 + c) * 8 + h) << 12;
    const bf16* Kt = fa.Kimg + tb;
    const bf16* Vt = fa.Vimg + tb;
    const int sr = tid >> 2, sp = tid & 3;

    // ---- phase 1: own chunk KV^T state + ksum ----
    {
      bfx8 k0 = *(const bfx8*)&Kt[sr * 64 + (((2 * sp) ^ (sr & 7)) << 3)];
      bfx8 k1 = *(const bfx8*)&Kt[sr * 64 + (((2 * sp + 1) ^ (sr & 7)) << 3)];
      bfx8 v0 = *(const bfx8*)&Vt[sr * 64 + (((2 * sp) ^ (sr & 7)) << 3)];
      bfx8 v1 = *(const bfx8*)&Vt[sr * 64 + (((2 * sp + 1) ^ (sr & 7)) << 3)];
#pragma unroll
      for (int q = 0; q < 8; ++q) {
        int d0 = sp * 16 + q, d1 = sp * 16 + 8 + q;
        KTs[d0 * 64 + (((sr >> 3) ^ (d0 & 7)) << 3) + (sr & 7)] = k0[q];
        KTs[d1 * 64 + (((sr >> 3) ^ (d1 & 7)) << 3) + (sr & 7)] = k1[q];
        VTs[d0 * 64 + (((sr >> 3) ^ (d0 & 7)) << 3) + (sr & 7)] = v0[q];
        VTs[d1 * 64 + (((sr >> 3) ^ (d1 & 7)) << 3) + (sr & 7)] = v1[q];
      }
    }
    __syncthreads();
    {
      int d = tid & 63, jp = tid >> 6;
      float s = 0.f;
#pragma unroll
      for (int q = 0; q < 16; ++q) {
        int j = jp * 16 + q;
        s += (float)KTs[d * 64 + (((j >> 3) ^ (d & 7)) << 3) + (j & 7)];
      }
      ksum_p[jp * 64 + d] = s;
    }
    {
      f32x4 kacc[4] = {};
#pragma unroll
      for (int ks = 0; ks < 2; ++ks) {
        int r = w * 16 + lm;
        bfx8 av = *(const bfx8*)&VTs[r * 64 + (((ks * 4 + lk) ^ (r & 7)) << 3)];
#pragma unroll
        for (int bn = 0; bn < 4; ++bn) {
          int e = bn * 16 + lm;
          bfx8 bk = *(const bfx8*)&KTs[e * 64 + (((ks * 4 + lk) ^ (e & 7)) << 3)];
          kacc[bn] = mfma16(av, bk, kacc[bn]);
        }
      }
      bf16* st = fa.KVb + (size_t)(bh * 16 + c) * 4096;
#pragma unroll
      for (int bn = 0; bn < 4; ++bn)
#pragma unroll
        for (int rg = 0; rg < 4; ++rg) {
          int e = w * 16 + lk * 4 + rg, d = bn * 16 + lm;
          st[e * 64 + d] = (bf16)kacc[bn][rg];
        }
    }
    __syncthreads();
    if (tid < 64)
      fa.ksums[(size_t)(bh * 16 + c) * 64 + tid] =
          ksum_p[tid] + ksum_p[64 + tid] + ksum_p[128 + tid] + ksum_p[192 + tid];
    __syncthreads();
    if (tid == 0) {
      __threadfence();
      astore(&fa.stflag[bh * 16 + c], 1);
    }

    // ---- phase 2: issue Q/K DMA, spin for prior states, then output ----
#pragma unroll
    for (int q = 0; q < 2; ++q) {
      int cb = (q * 4 + w) * 64;
      gl16(fa.Qimg + tb + (size_t)(cb + l) * 8, &Qs[cb * 8], l);
      gl16(fa.Kimg + tb + (size_t)(cb + l) * 8, &Ks[cb * 8], l);
    }
    if (tid == 0) {
      for (int cc = 0; cc < c; ++cc)
        while (!aload(&fa.stflag[bh * 16 + cc])) __builtin_amdgcn_s_sleep(2);
    }
    __syncthreads();
    {
      const int e = sr, dp = sp * 16;
      float s0[8] = {}, s1[8] = {};
      const bf16* kb = fa.KVb + (size_t)(bh * 16) * 4096 + e * 64 + dp;
      for (int cc = 0; cc < c; ++cc) {
        bfx8 x0 = *(const bfx8*)(kb + (size_t)cc * 4096);
        bfx8 x1 = *(const bfx8*)(kb + (size_t)cc * 4096 + 8);
#pragma unroll
        for (int q = 0; q < 8; ++q) { s0[q] += (float)x0[q]; s1[q] += (float)x1[q]; }
      }
      bfx8 y0, y1;
#pragma unroll
      for (int q = 0; q < 8; ++q) { y0[q] = (bf16)s0[q]; y1[q] = (bf16)s1[q]; }
      *(bfx8*)&KVL[e * 64 + (((2 * sp) ^ (e & 7)) << 3)] = y0;
      *(bfx8*)&KVL[e * 64 + (((2 * sp + 1) ^ (e & 7)) << 3)] = y1;
      if (tid < 64) {
        float s = 0.f;
        const float* kp = fa.ksums + (size_t)(bh * 16) * 64 + tid;
        for (int cc = 0; cc < c; ++cc) s += kp[(size_t)cc * 64];
        ksum[tid] = s;
      }
    }
    __syncthreads();

    f32x4 sacc[4] = {};
    bfx8 aq[2];
#pragma unroll
    for (int ks = 0; ks < 2; ++ks) {
      int r = w * 16 + lm;
      aq[ks] = *(const bfx8*)&Qs[r * 64 + (((ks * 4 + lk) ^ (r & 7)) << 3)];
#pragma unroll
      for (int bn = 0; bn < 4; ++bn) {
        int rb = bn * 16 + lm;
        bfx8 bk = *(const bfx8*)&Ks[rb * 64 + (((ks * 4 + lk) ^ (rb & 7)) << 3)];
        sacc[bn] = mfma16(aq[ks], bk, sacc[bn]);
      }
    }
    float prs[4] = {0.f, 0.f, 0.f, 0.f};
#pragma unroll
    for (int bn = 0; bn < 4; ++bn)
#pragma unroll
      for (int rg = 0; rg < 4; ++rg) {
        int i = w * 16 + lk * 4 + rg, j = bn * 16 + lm;
        float v = (j <= i) ? sacc[bn][rg] : 0.f;
        prs[rg] += v;
        Ss[i * 64 + (((j >> 3) ^ (i & 7)) << 3) + (j & 7)] = (bf16)v;
      }
#pragma unroll
    for (int m = 1; m < 16; m <<= 1) {
#pragma unroll
      for (int rg = 0; rg < 4; ++rg) prs[rg] += __shfl_xor(prs[rg], m, 64);
    }
    if (lm == 0) {
#pragma unroll
      for (int rg = 0; rg < 4; ++rg) den_i[w * 16 + lk * 4 + rg] = prs[rg];
    }
    {
      float s = 0.f;
#pragma unroll
      for (int q = 0; q < 16; ++q) {
        int d = sp * 16 + q;
        s += (float)Qs[sr * 64 + (((d >> 3) ^ (sr & 7)) << 3) + (d & 7)] * ksum[d];
      }
      den_p[sp * 64 + sr] = s;
    }
    __syncthreads();

    if (tid < 64)
      den_all[tid] =
          den_i[tid] + den_p[tid] + den_p[64 + tid] + den_p[128 + tid] + den_p[192 + tid];
    f32x4 oacc[4] = {};
#pragma unroll
    for (int ks = 0; ks < 2; ++ks) {
      int r = w * 16 + lm;
      bfx8 as_ = *(const bfx8*)&Ss[r * 64 + (((ks * 4 + lk) ^ (r & 7)) << 3)];
#pragma unroll
      for (int bn = 0; bn < 4; ++bn) {
        int e = bn * 16 + lm;
        bfx8 bv = *(const bfx8*)&VTs[e * 64 + (((ks * 4 + lk) ^ (e & 7)) << 3)];
        oacc[bn] = mfma16(as_, bv, oacc[bn]);
        bfx8 bkv = *(const bfx8*)&KVL[e * 64 + (((ks * 4 + lk) ^ (e & 7)) << 3)];
        oacc[bn] = mfma16(aq[ks], bkv, oacc[bn]);
      }
    }
    __syncthreads();

    bf16* ot = fa.Obsw + tb;
#pragma unroll
    for (int bn = 0; bn < 4; ++bn)
#pragma unroll
      for (int rg = 0; rg < 4; ++rg) {
        int i = w * 16 + lk * 4 + rg, e = bn * 16 + lm;
        float o = oacc[bn][rg] / (den_all[i] + 1e-6f);
        ot[img_off(i, e)] = (bf16)o;
      }
    __syncthreads();
    if (tid == 0) {
      __threadfence();
      __hip_atomic_fetch_add(&fa.obcnt[b * 16 + c], 1, __ATOMIC_RELEASE,
                             __HIP_MEMORY_SCOPE_AGENT);
    }
  } else {
    // =================== Role B: output GEMM ===================
    const int idx = bid - 512;
    const int tm = (idx >> 2) * 64, tn = (idx & 3) * 128, rt = idx >> 2;
    bf16* As = (bf16*)smem;
    bf16* Bs = (bf16*)(smem + 8192);

    if (tid == 0) {
      while (aload(&fa.obcnt[rt]) < 8) __builtin_amdgcn_s_sleep(8);
    }
    __syncthreads();

    f32x4 acc[2][4] = {};
    for (int kt = 0; kt < 8; ++kt) {
      const bf16* bsrc = fa.Woimg + (size_t)(kt * 8 + (idx & 3) * 2) * 4096;
#pragma unroll
      for (int q = 0; q < 4; ++q) {
        int cb = (q * 4 + w) * 64;
        gl16(bsrc + (size_t)(cb + l) * 8, &Bs[cb * 8], l);
      }
      const bf16* asrc = fa.Obsw + ((size_t)((tm >> 6) * 8 + kt) << 12);
#pragma unroll
      for (int q = 0; q < 2; ++q) {
        int cb = (q * 4 + w) * 64;
        gl16(asrc + (size_t)(cb + l) * 8, &As[cb * 8], l);
      }
      __syncthreads();
#pragma unroll
      for (int ks = 0; ks < 2; ++ks) {
        bfx8 af[2], bfr[4];
#pragma unroll
        for (int i = 0; i < 2; ++i) {
          int ra = wm * 32 + i * 16 + lm;
          af[i] = *(const bfx8*)&As[ra * 64 + (((ks * 4 + lk) ^ (ra & 7)) << 3)];
        }
#pragma unroll
        for (int j = 0; j < 4; ++j) {
          int rb = wn * 64 + j * 16 + lm;
          bfr[j] = *(const bfx8*)&Bs[rb * 64 + (((ks * 4 + lk) ^ (rb & 7)) << 3)];
        }
#pragma unroll
        for (int i = 0; i < 2; ++i)
#pragma unroll
          for (int j = 0; j < 4; ++j)
            acc[i][j] = mfma16(af[i], bfr[j], acc[i][j]);
      }
      __syncthreads();
    }
#pragma unroll
    for (int i = 0; i < 2; ++i)
#pragma unroll
      for (int j = 0; j < 4; ++j)
#pragma unroll
        for (int r = 0; r < 4; ++r) {
          int m = tm + wm * 32 + i * 16 + lk * 4 + r;
          int n = tn + wn * 64 + j * 16 + lm;
          fa.out[(size_t)m * 512 + n] = acc[i][j][r];
        }
  }
}

// ---------------- launch ----------------
extern "C" void kernel_launch(void* const* d_in, const int* in_sizes, int n_in,
                              void* d_out, int out_size, void* d_ws, size_t ws_size,
                              hipStream_t stream) {
  const float* Q = (const float*)d_in[0];
  const float* K = (const float*)d_in[1];
  const float* V = (const float*)d_in[2];
  const float* Wq = (const float*)d_in[3];
  const float* Wk = (const float*)d_in[4];
  const float* Wv = (const float*)d_in[5];
  const float* Wo = (const float*)d_in[6];
  (void)in_sizes; (void)n_in; (void)out_size; (void)ws_size;

  char* wsp = (char*)d_ws;
  const size_t MB = 1ull << 20;
  const size_t HK = 512 * 1024;
  bf16* Wimg[4];
  for (int z = 0; z < 4; ++z) Wimg[z] = (bf16*)(wsp + z * HK);
  bf16* Qimg = (bf16*)(wsp + 4 * MB);
  bf16* Kimg = (bf16*)(wsp + 8 * MB);
  bf16* Vimg = (bf16*)(wsp + 12 * MB);
  bf16* Obsw = (bf16*)(wsp + 16 * MB);
  bf16* KVb = (bf16*)(wsp + 20 * MB);
  float* ksums = (float*)(wsp + 24 * MB);
  int* flags = (int*)(wsp + 28 * MB);  // stflag[512] + obcnt[64]

  CvtArgs ca;
  ca.src[0] = Wq; ca.src[1] = Wk; ca.src[2] = Wv; ca.src[3] = Wo;
  ca.dst[0] = Wimg[0]; ca.dst[1] = Wimg[1]; ca.dst[2] = Wimg[2]; ca.dst[3] = Wimg[3];
  ca.flags = flags;
  cvt_w<<<dim3(16, 4), 256, 0, stream>>>(ca);

  GemmArgs g1;
  g1.A[0] = Q;  g1.A[1] = K;  g1.A[2] = V;
  g1.Bt[0] = Wimg[0]; g1.Bt[1] = Wimg[1]; g1.Bt[2] = Wimg[2];
  g1.ob[0] = Qimg; g1.ob[1] = Kimg; g1.ob[2] = Vimg;
  g1.of = nullptr;
  g1.phi_upto = 2;
  gemm_bt<true, false><<<dim3(64, 4, 3), 512, 0, stream>>>(g1);

  FusedArgs fa;
  fa.Qimg = Qimg; fa.Kimg = Kimg; fa.Vimg = Vimg; fa.Woimg = Wimg[3];
  fa.KVb = KVb; fa.Obsw = Obsw;
  fa.ksums = ksums;
  fa.out = (float*)d_out;
  fa.stflag = flags;
  fa.obcnt = flags + 512;
  attn_fused<<<768, 256, 0, stream>>>(fa);
}

// Round 18
// 46.737 us; speedup vs baseline: 4.0756x; 4.0756x over previous
//
#include <hip/hip_runtime.h>
#include <stdint.h>

typedef __bf16 bf16;
typedef __attribute__((ext_vector_type(8))) __bf16 bfx8;
typedef __attribute__((ext_vector_type(4))) float f32x4;

__device__ inline f32x4 mfma16(bfx8 a, bfx8 b, f32x4 c) {
  return __builtin_amdgcn_mfma_f32_16x16x32_bf16(a, b, c, 0, 0, 0);
}

// Async 16B global->LDS. lbase must be wave-uniform; HW adds lane*16.
__device__ inline void gl16(const bf16* g, bf16* lbase, int lane) {
#if __has_builtin(__builtin_amdgcn_global_load_lds)
  (void)lane;
  __builtin_amdgcn_global_load_lds(
      (const __attribute__((address_space(1))) void*)g,
      (__attribute__((address_space(3))) void*)lbase, 16, 0, 0);
#else
  *(bfx8*)(lbase + lane * 8) = *(const bfx8*)g;
#endif
}

// Image convention: 64x64 bf16 tile stored as 4096 elems, 16B chunks
// XOR-swizzled per row: element (i,e) lives at i*64 + (((e>>3)^(i&7))<<3) + (e&7).
__device__ inline int img_off(int i, int e) {
  return i * 64 + ((((e >> 3) ^ (i & 7)) << 3)) + (e & 7);
}

// ---------------- weight fp32 -> bf16 tile-image ----------------
struct CvtArgs {
  const float* src[4];
  bf16* dst[4];
};
__global__ __launch_bounds__(256) void cvt_w(CvtArgs ca) {
  const int z = blockIdx.y;
  const int T = blockIdx.x * 256 + threadIdx.x;  // 4096 threads
  const int n = T >> 3, s8 = T & 7, i = n & 63, nt = n >> 6;
  const float* src = ca.src[z];
  bf16* dst = ca.dst[z];
#pragma unroll
  for (int kt = 0; kt < 8; ++kt) {
    const float* s = src + (size_t)n * 512 + kt * 64 + ((s8 ^ (i & 7)) << 3);
    f32x4 x0 = *(const f32x4*)s, x1 = *(const f32x4*)(s + 4);
    bfx8 v;
    v[0] = (bf16)x0[0]; v[1] = (bf16)x0[1]; v[2] = (bf16)x0[2]; v[3] = (bf16)x0[3];
    v[4] = (bf16)x1[0]; v[5] = (bf16)x1[1]; v[6] = (bf16)x1[2]; v[7] = (bf16)x1[3];
    *(bfx8*)&dst[(size_t)(kt * 8 + nt) * 4096 + i * 64 + s8 * 8] = v;
  }
}

// ---------------- GEMM: C[m][n] = sum_k A[m][k] * Bt[n][k] ----------------
// Tile 64x128, BK=64, 512 threads = 8 waves (2x4), each wave owns 32x32 out.
// M=4096, N=512, K=512. B via gl16 from weight image; A fp32 reg-convert
// (proj) or gl16 image (out GEMM). Output: bf16 tile-image or fp32 row-major.
struct GemmArgs {
  const void* A[3];
  const bf16* Bt[3];  // weight image
  bf16* ob[3];        // bf16 image out
  float* of;          // fp32 row-major out
  int phi_upto;       // z < phi_upto applies phi = elu(x)+1
};

template <bool AF32, bool OUTF>
__global__ __launch_bounds__(512) void gemm_bt(GemmArgs ga) {
  const int z = blockIdx.z;
  const void* Ag = ga.A[z];
  const bf16* Bg = ga.Bt[z];
  const int tm = blockIdx.x * 64, by = blockIdx.y, tn = by * 128;
  const int tid = threadIdx.x, l = tid & 63, w = tid >> 6;
  const int wm = w >> 2, wn = w & 3, lm = l & 15, lk = l >> 4;

  __shared__ __align__(16) bf16 As[64 * 64];    // 8 KB
  __shared__ __align__(16) bf16 Bs[128 * 64];   // 16 KB

  f32x4 acc[2][2] = {};

  for (int kt = 0; kt < 8; ++kt) {
    // ---- B tile: 1024 chunks via async DMA (2 issues/wave), zero VALU ----
    const bf16* bsrc = Bg + (size_t)(kt * 8 + by * 2) * 4096;
#pragma unroll
    for (int q = 0; q < 2; ++q) {
      int cb = (q * 8 + w) * 64;
      gl16(bsrc + (size_t)(cb + l) * 8, &Bs[cb * 8], l);
    }
    // ---- A tile ----
    if (AF32) {
      // fp32 row-major -> convert -> swizzled LDS; 1 chunk per thread
      int row = tid >> 3, t8 = tid & 7;
      const float* s = (const float*)Ag + (size_t)(tm + row) * 512 + kt * 64 + t8 * 8;
      f32x4 x0 = *(const f32x4*)s, x1 = *(const f32x4*)(s + 4);
      bfx8 v;
      v[0] = (bf16)x0[0]; v[1] = (bf16)x0[1]; v[2] = (bf16)x0[2]; v[3] = (bf16)x0[3];
      v[4] = (bf16)x1[0]; v[5] = (bf16)x1[1]; v[6] = (bf16)x1[2]; v[7] = (bf16)x1[3];
      *(bfx8*)&As[row * 64 + ((t8 ^ (row & 7)) << 3)] = v;
    } else {
      // bf16 image -> async DMA (1 issue/wave)
      const bf16* asrc = (const bf16*)Ag + ((size_t)((tm >> 6) * 8 + kt) << 12);
      int cb = w * 64;
      gl16(asrc + (size_t)(cb + l) * 8, &As[cb * 8], l);
    }
    __syncthreads();
#pragma unroll
    for (int ks = 0; ks < 2; ++ks) {
      bfx8 af[2], bfr[2];
#pragma unroll
      for (int i = 0; i < 2; ++i) {
        int ra = wm * 32 + i * 16 + lm;
        af[i] = *(const bfx8*)&As[ra * 64 + (((ks * 4 + lk) ^ (ra & 7)) << 3)];
        int rb = wn * 32 + i * 16 + lm;
        bfr[i] = *(const bfx8*)&Bs[rb * 64 + (((ks * 4 + lk) ^ (rb & 7)) << 3)];
      }
#pragma unroll
      for (int i = 0; i < 2; ++i)
#pragma unroll
        for (int j = 0; j < 2; ++j)
          acc[i][j] = mfma16(af[i], bfr[j], acc[i][j]);
    }
    __syncthreads();
  }

  const bool phi = z < ga.phi_upto;
#pragma unroll
  for (int i = 0; i < 2; ++i)
#pragma unroll
    for (int j = 0; j < 2; ++j)
#pragma unroll
      for (int r = 0; r < 4; ++r) {
        int m = tm + wm * 32 + i * 16 + lk * 4 + r;
        int n = tn + wn * 32 + j * 16 + lm;
        float v = acc[i][j][r];
        if (phi) v = v > 0.f ? v + 1.f : __expf(v);
        if (OUTF) {
          ga.of[(size_t)m * 512 + n] = v;
        } else {
          ga.ob[z][((size_t)((m >> 6) * 8 + (n >> 6)) << 12) + img_off(m & 63, n & 63)] =
              (bf16)v;
        }
      }
}

// ---------------- attention stage 1: per-chunk KV^T (bf16) + ksum ----------------
__global__ __launch_bounds__(256) void chunk_kv(const bf16* __restrict__ Kimg,
                                                const bf16* __restrict__ Vimg,
                                                bf16* __restrict__ KVb,
                                                float* __restrict__ ksums) {
  const int bh = blockIdx.x, c = blockIdx.y, b = bh >> 3, h = bh & 7;
  const int tid = threadIdx.x, l = tid & 63, w = tid >> 6, lm = l & 15, lk = l >> 4;
  __shared__ __align__(16) bf16 KTs[64 * 64];  // [d][j] swizzled
  __shared__ __align__(16) bf16 VTs[64 * 64];  // [e][j] swizzled
  __shared__ float ksum_p[256];

  const size_t tb = (size_t)((b * 16 + c) * 8 + h) << 12;
  const bf16* Kt = Kimg + tb;
  const bf16* Vt = Vimg + tb;
  const int sr = tid >> 2, sp = tid & 3;
  {
    bfx8 k0 = *(const bfx8*)&Kt[sr * 64 + (((2 * sp) ^ (sr & 7)) << 3)];
    bfx8 k1 = *(const bfx8*)&Kt[sr * 64 + (((2 * sp + 1) ^ (sr & 7)) << 3)];
    bfx8 v0 = *(const bfx8*)&Vt[sr * 64 + (((2 * sp) ^ (sr & 7)) << 3)];
    bfx8 v1 = *(const bfx8*)&Vt[sr * 64 + (((2 * sp + 1) ^ (sr & 7)) << 3)];
#pragma unroll
    for (int q = 0; q < 8; ++q) {
      int d0 = sp * 16 + q, d1 = sp * 16 + 8 + q;
      KTs[d0 * 64 + (((sr >> 3) ^ (d0 & 7)) << 3) + (sr & 7)] = k0[q];
      KTs[d1 * 64 + (((sr >> 3) ^ (d1 & 7)) << 3) + (sr & 7)] = k1[q];
      VTs[d0 * 64 + (((sr >> 3) ^ (d0 & 7)) << 3) + (sr & 7)] = v0[q];
      VTs[d1 * 64 + (((sr >> 3) ^ (d1 & 7)) << 3) + (sr & 7)] = v1[q];
    }
  }
  __syncthreads();
  {
    int d = tid & 63, jp = tid >> 6;
    float s = 0.f;
#pragma unroll
    for (int q = 0; q < 16; ++q) {
      int j = jp * 16 + q;
      s += (float)KTs[d * 64 + (((j >> 3) ^ (d & 7)) << 3) + (j & 7)];
    }
    ksum_p[jp * 64 + d] = s;
  }
  f32x4 kacc[4] = {};
#pragma unroll
  for (int ks = 0; ks < 2; ++ks) {
    int r = w * 16 + lm;
    bfx8 av = *(const bfx8*)&VTs[r * 64 + (((ks * 4 + lk) ^ (r & 7)) << 3)];
#pragma unroll
    for (int bn = 0; bn < 4; ++bn) {
      int e = bn * 16 + lm;
      bfx8 bk = *(const bfx8*)&KTs[e * 64 + (((ks * 4 + lk) ^ (e & 7)) << 3)];
      kacc[bn] = mfma16(av, bk, kacc[bn]);
    }
  }
  bf16* st = KVb + (size_t)(bh * 16 + c) * 4096;
#pragma unroll
  for (int bn = 0; bn < 4; ++bn)
#pragma unroll
    for (int rg = 0; rg < 4; ++rg) {
      int e = w * 16 + lk * 4 + rg, d = bn * 16 + lm;
      st[e * 64 + d] = (bf16)kacc[bn][rg];
    }
  __syncthreads();
  if (tid < 64)
    ksums[(size_t)(bh * 16 + c) * 64 + tid] =
        ksum_p[tid] + ksum_p[64 + tid] + ksum_p[128 + tid] + ksum_p[192 + tid];
}

// ---------------- attention stage 2: per-chunk output (heavy chunks first) ----------------
__global__ __launch_bounds__(256) void chunk_out(const bf16* __restrict__ Qimg,
                                                 const bf16* __restrict__ Kimg,
                                                 const bf16* __restrict__ Vimg,
                                                 const bf16* __restrict__ KVb,
                                                 const float* __restrict__ ksums,
                                                 bf16* __restrict__ Obsw) {
  const int bh = blockIdx.x, c = 15 - blockIdx.y, b = bh >> 3, h = bh & 7;
  const int tid = threadIdx.x, l = tid & 63, w = tid >> 6, lm = l & 15, lk = l >> 4;

  __shared__ __align__(16) bf16 Qs[64 * 64];   // [i][d] image via DMA
  __shared__ __align__(16) bf16 Ks[64 * 64];   // [j][d] image via DMA
  __shared__ __align__(16) bf16 VTs[64 * 64];  // [e][j] swizzled
  __shared__ __align__(16) bf16 Ss[64 * 64];   // [i][j] masked S
  __shared__ __align__(16) bf16 KVL[64 * 64];  // [e][d] prefix state, swizzled
  __shared__ float ksum[64], den_i[64], den_all[64], den_p[256];

  const size_t tb = (size_t)((b * 16 + c) * 8 + h) << 12;
  const int sr = tid >> 2, sp = tid & 3;

#pragma unroll
  for (int q = 0; q < 2; ++q) {
    int cb = (q * 4 + w) * 64;
    gl16(Qimg + tb + (size_t)(cb + l) * 8, &Qs[cb * 8], l);
    gl16(Kimg + tb + (size_t)(cb + l) * 8, &Ks[cb * 8], l);
  }
  {
    const bf16* Vt = Vimg + tb;
    bfx8 v0 = *(const bfx8*)&Vt[sr * 64 + (((2 * sp) ^ (sr & 7)) << 3)];
    bfx8 v1 = *(const bfx8*)&Vt[sr * 64 + (((2 * sp + 1) ^ (sr & 7)) << 3)];
#pragma unroll
    for (int q = 0; q < 8; ++q) {
      int d0 = sp * 16 + q, d1 = sp * 16 + 8 + q;
      VTs[d0 * 64 + (((sr >> 3) ^ (d0 & 7)) << 3) + (sr & 7)] = v0[q];
      VTs[d1 * 64 + (((sr >> 3) ^ (d1 & 7)) << 3) + (sr & 7)] = v1[q];
    }
  }
  {
    const int e = sr, dp = sp * 16;
    float s0[8] = {}, s1[8] = {};
    const bf16* kb = KVb + (size_t)(bh * 16) * 4096 + e * 64 + dp;
    for (int cc = 0; cc < c; ++cc) {
      bfx8 x0 = *(const bfx8*)(kb + (size_t)cc * 4096);
      bfx8 x1 = *(const bfx8*)(kb + (size_t)cc * 4096 + 8);
#pragma unroll
      for (int q = 0; q < 8; ++q) { s0[q] += (float)x0[q]; s1[q] += (float)x1[q]; }
    }
    bfx8 y0, y1;
#pragma unroll
    for (int q = 0; q < 8; ++q) { y0[q] = (bf16)s0[q]; y1[q] = (bf16)s1[q]; }
    *(bfx8*)&KVL[e * 64 + (((2 * sp) ^ (e & 7)) << 3)] = y0;
    *(bfx8*)&KVL[e * 64 + (((2 * sp + 1) ^ (e & 7)) << 3)] = y1;
    if (tid < 64) {
      float s = 0.f;
      const float* kp = ksums + (size_t)(bh * 16) * 64 + tid;
      for (int cc = 0; cc < c; ++cc) s += kp[(size_t)cc * 64];
      ksum[tid] = s;
    }
  }
  __syncthreads();

  // ---------- phase A: S, mask, rowsum, den partials ----------
  f32x4 sacc[4] = {};
  bfx8 aq[2];
#pragma unroll
  for (int ks = 0; ks < 2; ++ks) {
    int r = w * 16 + lm;
    aq[ks] = *(const bfx8*)&Qs[r * 64 + (((ks * 4 + lk) ^ (r & 7)) << 3)];
#pragma unroll
    for (int bn = 0; bn < 4; ++bn) {
      int rb = bn * 16 + lm;
      bfx8 bk = *(const bfx8*)&Ks[rb * 64 + (((ks * 4 + lk) ^ (rb & 7)) << 3)];
      sacc[bn] = mfma16(aq[ks], bk, sacc[bn]);
    }
  }
  float prs[4] = {0.f, 0.f, 0.f, 0.f};
#pragma unroll
  for (int bn = 0; bn < 4; ++bn)
#pragma unroll
    for (int rg = 0; rg < 4; ++rg) {
      int i = w * 16 + lk * 4 + rg, j = bn * 16 + lm;
      float v = (j <= i) ? sacc[bn][rg] : 0.f;
      prs[rg] += v;
      Ss[i * 64 + (((j >> 3) ^ (i & 7)) << 3) + (j & 7)] = (bf16)v;
    }
#pragma unroll
  for (int m = 1; m < 16; m <<= 1) {
#pragma unroll
    for (int rg = 0; rg < 4; ++rg) prs[rg] += __shfl_xor(prs[rg], m, 64);
  }
  if (lm == 0) {
#pragma unroll
    for (int rg = 0; rg < 4; ++rg) den_i[w * 16 + lk * 4 + rg] = prs[rg];
  }
  {
    float s = 0.f;
#pragma unroll
    for (int q = 0; q < 16; ++q) {
      int d = sp * 16 + q;
      s += (float)Qs[sr * 64 + (((d >> 3) ^ (sr & 7)) << 3) + (d & 7)] * ksum[d];
    }
    den_p[sp * 64 + sr] = s;
  }
  __syncthreads();

  // ---------- phase B: den finalize + num MFMAs ----------
  if (tid < 64)
    den_all[tid] = den_i[tid] + den_p[tid] + den_p[64 + tid] + den_p[128 + tid] + den_p[192 + tid];
  f32x4 oacc[4] = {};
#pragma unroll
  for (int ks = 0; ks < 2; ++ks) {
    int r = w * 16 + lm;
    bfx8 as_ = *(const bfx8*)&Ss[r * 64 + (((ks * 4 + lk) ^ (r & 7)) << 3)];
#pragma unroll
    for (int bn = 0; bn < 4; ++bn) {
      int e = bn * 16 + lm;
      bfx8 bv = *(const bfx8*)&VTs[e * 64 + (((ks * 4 + lk) ^ (e & 7)) << 3)];
      oacc[bn] = mfma16(as_, bv, oacc[bn]);  // intra: S~ @ V
      bfx8 bkv = *(const bfx8*)&KVL[e * 64 + (((ks * 4 + lk) ^ (e & 7)) << 3)];
      oacc[bn] = mfma16(aq[ks], bkv, oacc[bn]);  // inter: Qf @ KV_prefix
    }
  }
  __syncthreads();

  bf16* ot = Obsw + tb;
#pragma unroll
  for (int bn = 0; bn < 4; ++bn)
#pragma unroll
    for (int rg = 0; rg < 4; ++rg) {
      int i = w * 16 + lk * 4 + rg, e = bn * 16 + lm;
      float o = oacc[bn][rg] / (den_all[i] + 1e-6f);
      ot[img_off(i, e)] = (bf16)o;
    }
}

// ---------------- launch ----------------
extern "C" void kernel_launch(void* const* d_in, const int* in_sizes, int n_in,
                              void* d_out, int out_size, void* d_ws, size_t ws_size,
                              hipStream_t stream) {
  const float* Q = (const float*)d_in[0];
  const float* K = (const float*)d_in[1];
  const float* V = (const float*)d_in[2];
  const float* Wq = (const float*)d_in[3];
  const float* Wk = (const float*)d_in[4];
  const float* Wv = (const float*)d_in[5];
  const float* Wo = (const float*)d_in[6];
  (void)in_sizes; (void)n_in; (void)out_size; (void)ws_size;

  char* wsp = (char*)d_ws;
  const size_t MB = 1ull << 20;
  const size_t HK = 512 * 1024;
  bf16* Wimg[4];
  for (int z = 0; z < 4; ++z) Wimg[z] = (bf16*)(wsp + z * HK);
  bf16* Qimg = (bf16*)(wsp + 4 * MB);
  bf16* Kimg = (bf16*)(wsp + 8 * MB);
  bf16* Vimg = (bf16*)(wsp + 12 * MB);
  bf16* Obsw = (bf16*)(wsp + 16 * MB);
  bf16* KVb = (bf16*)(wsp + 20 * MB);
  float* ksums = (float*)(wsp + 24 * MB);

  CvtArgs ca;
  ca.src[0] = Wq; ca.src[1] = Wk; ca.src[2] = Wv; ca.src[3] = Wo;
  ca.dst[0] = Wimg[0]; ca.dst[1] = Wimg[1]; ca.dst[2] = Wimg[2]; ca.dst[3] = Wimg[3];
  cvt_w<<<dim3(16, 4), 256, 0, stream>>>(ca);

  GemmArgs g1;
  g1.A[0] = Q;  g1.A[1] = K;  g1.A[2] = V;
  g1.Bt[0] = Wimg[0]; g1.Bt[1] = Wimg[1]; g1.Bt[2] = Wimg[2];
  g1.ob[0] = Qimg; g1.ob[1] = Kimg; g1.ob[2] = Vimg;
  g1.of = nullptr;
  g1.phi_upto = 2;
  gemm_bt<true, false><<<dim3(64, 4, 3), 512, 0, stream>>>(g1);

  chunk_kv<<<dim3(32, 16), 256, 0, stream>>>(Kimg, Vimg, KVb, ksums);
  chunk_out<<<dim3(32, 16), 256, 0, stream>>>(Qimg, Kimg, Vimg, KVb, ksums, Obsw);

  GemmArgs g2;
  g2.A[0] = Obsw; g2.A[1] = nullptr; g2.A[2] = nullptr;
  g2.Bt[0] = Wimg[3]; g2.Bt[1] = nullptr; g2.Bt[2] = nullptr;
  g2.ob[0] = nullptr; g2.ob[1] = nullptr; g2.ob[2] = nullptr;
  g2.of = (float*)d_out;
  g2.phi_upto = 0;
  gemm_bt<false, true><<<dim3(64, 4, 1), 512, 0, stream>>>(g2);
}